// Round 5
// baseline (309.176 us; speedup 1.0000x reference)
//
#include <hip/hip_runtime.h>
#include <hip/hip_bf16.h>

#define BDIM 2048
#define WDIM 128
#define FDIM 8
#define HDIM 256

typedef __bf16 b8 __attribute__((ext_vector_type(8)));
typedef __bf16 b4 __attribute__((ext_vector_type(4)));
typedef float f32x4 __attribute__((ext_vector_type(4)));

// workspace layout (bytes), all 16B aligned
#define OFF_RZ  0                 // 256 frags * 1KB (r,z Whh A-frags)
#define OFF_N   262144            // 128 frags * 1KB (n Whh A-frags)
#define OFF_WIH 393216            // 48 frags * 1KB  (Wih A-frags + bias in k=8)
#define OFF_WP  442368            // 256 frags * 1KB (Wp B-frags)
#define OFF_XB  704512            // 2048*128*8 bf16 = 4194304
// total 4,898,816 B

// dynamic LDS: [0,16K) h dbuf (2x8KB) ; [16K,64K) wih frags (8 waves x 6 x 1KB)
// tail overlay: [0,16K) lastb[16][512] bf16 ; [16K,32K) ybuf[16][256] f32
#define SMEM_BYTES 65536

#define MFMA(a,b,c) __builtin_amdgcn_mfma_f32_16x16x32_bf16((a),(b),(c),0,0,0)

static __device__ __forceinline__ float sig_(float v) {
    return __builtin_amdgcn_rcpf(1.0f + __expf(-v));
}
static __device__ __forceinline__ float tanh_(float v) {
    // tanh(v) = 1 - 2/(exp(2v)+1); saturates correctly at +-inf
    return fmaf(-2.0f, __builtin_amdgcn_rcpf(1.0f + __expf(2.0f * v)), 1.0f);
}

// ---------------- pack: weights/x -> bf16 MFMA fragments ----------------
// A-frag (16x16x32): lane l holds A[i = l&15][k = kt*32 + (l>>4)*8 + e]
// B-frag:            lane l holds B[k = kt*32 + (l>>4)*8 + e][j = l&15]
__global__ void pack_kernel(const float* __restrict__ x,
                            const float* __restrict__ Wih_f,
                            const float* __restrict__ Whh_f,
                            const float* __restrict__ bih_f,
                            const float* __restrict__ bhh_f,
                            const float* __restrict__ Wp,
                            unsigned char* __restrict__ ws)
{
    int idx = blockIdx.x * 256 + threadIdx.x;
    if (idx < 16384) {                       // r,z Whh A-frags: f = (w*4+2g+nt)*8+kt
        int l = idx & 63, f = idx >> 6;
        int kt = f & 7, nt = (f >> 3) & 1, g = (f >> 4) & 1, w = f >> 5;
        int gch = g * HDIM + 32 * w + 16 * nt + (l & 15);
        int kb = kt * 32 + (l >> 4) * 8;
        b8 v;
        #pragma unroll
        for (int e = 0; e < 8; ++e) v[e] = (__bf16)Whh_f[gch * HDIM + kb + e];
        ((b8*)(ws + OFF_RZ))[idx] = v;
    } else if (idx < 24576) {                // n Whh A-frags: f = (w*2+nt)*8+kt
        int j = idx - 16384;
        int l = j & 63, f = j >> 6;
        int kt = f & 7, nt = (f >> 3) & 1, w = f >> 4;
        int gch = 2 * HDIM + 32 * w + 16 * nt + (l & 15);
        int kb = kt * 32 + (l >> 4) * 8;
        b8 v;
        #pragma unroll
        for (int e = 0; e < 8; ++e) v[e] = (__bf16)Whh_f[gch * HDIM + kb + e];
        ((b8*)(ws + OFF_N))[j] = v;
    } else if (idx < 27648) {                // Wih A-frags (K=8 real, bias at k=8)
        int j = idx - 24576;
        int l = j & 63, f = j >> 6;
        int nt = f & 1, q = f >> 1, g = q % 3, w = q / 3;
        int gch = g * HDIM + 32 * w + 16 * nt + (l & 15);
        int lq = l >> 4;
        b8 v;
        #pragma unroll
        for (int e = 0; e < 8; ++e) v[e] = (__bf16)0.0f;
        if (lq == 0) {
            #pragma unroll
            for (int e = 0; e < 8; ++e) v[e] = (__bf16)Wih_f[gch * FDIM + e];
        } else if (lq == 1) {
            float b = (g == 2) ? bih_f[gch] : (bih_f[gch] + bhh_f[gch]);
            v[0] = (__bf16)b;                // pairs with 1.0 in x B-frag k=8
        }
        ((b8*)(ws + OFF_WIH))[j] = v;
    } else if (idx < 44032) {                // Wp B-frags
        int j = idx - 27648;
        int l = j & 63, nk = j >> 6;
        int NT = nk >> 4, kt = nk & 15;
        int col = NT * 16 + (l & 15);
        int kb = kt * 32 + (l >> 4) * 8;
        b8 v;
        #pragma unroll
        for (int e = 0; e < 8; ++e) v[e] = (__bf16)Wp[col * (2 * HDIM) + kb + e];
        ((b8*)(ws + OFF_WP))[j] = v;
    } else if (idx < 44032 + 262144) {       // x -> bf16 rows [row][t][8]
        int j = idx - 44032;
        const float* src = x + j * 8;
        b8 v;
        #pragma unroll
        for (int e = 0; e < 8; ++e) v[e] = (__bf16)src[e];
        ((b8*)(ws + OFF_XB))[j] = v;
    }
}

// ---------------- fused GRU (transposed MFMA, all Whh in regs) ----------------
// 128 blocks x 512 threads (8 waves). Block owns 16 batch rows.
// Wave w owns gate channels [32w, 32w+32) of r, z, n (as M-tiles).
// ALL Whh frags (r,z,n = 48) pinned in regs/AGPRs; Wih read from LDS per step.
// D[i=gatech][j=batchrow]: lane holds batchrow = l&15, gatech = 4*(l>>4)+j.
__global__ __launch_bounds__(512, 2)
void gru_main_kernel(const float* __restrict__ x,
                     const float* __restrict__ bhh_f,
                     const float* __restrict__ Wih_b, const float* __restrict__ bih_b,
                     const float* __restrict__ bhh_b,
                     const float* __restrict__ bp,
                     const float* __restrict__ gamma, const float* __restrict__ beta,
                     const unsigned char* __restrict__ ws,
                     float* __restrict__ out)
{
    extern __shared__ __align__(16) unsigned char smem[];
    __bf16* hbB = (__bf16*)smem;                            // [0,16K) h dbuf
    b8* wihL = (b8*)(smem + 16384);                         // [16K,64K) wih frags
    __bf16 (*lastb)[2 * HDIM] = (__bf16(*)[2 * HDIM])smem;  // tail overlay
    float  (*ybuf)[HDIM]      = (float(*)[HDIM])(smem + 16384);

    const int tid = threadIdx.x, lane = tid & 63, w = tid >> 6;
    const int l15 = lane & 15, lq = lane >> 4;
    const int blockRow = blockIdx.x * 16;

    const b8* wsRZ = (const b8*)(ws + OFF_RZ);
    const b8* wsN  = (const b8*)(ws + OFF_N);
    const b8* wsWI = (const b8*)(ws + OFF_WIH);
    const b8* wsWP = (const b8*)(ws + OFF_WP);
    const b8* xB   = (const b8*)(ws + OFF_XB);

    const f32x4 zero4 = {0.f, 0.f, 0.f, 0.f};

    // zero h dbuf: 512 threads x 16B x 2
    *(f32x4*)(smem + tid * 16) = zero4;
    *(f32x4*)(smem + 8192 + tid * 16) = zero4;

    // stage this wave's 6 Wih frags into LDS (one-time; contiguous per wave)
    {
        const b8* src = wsWI + (w * 6) * 64 + lane;
        b8* dst = wihL + (w * 6) * 64 + lane;
        #pragma unroll
        for (int i = 0; i < 6; ++i) dst[i * 64] = src[i * 64];
    }

    // register-resident A-frags: ALL Whh (r,z,n = 48 frags), PINNED
    b8 whr[2][8], whz[2][8], wnn[2][8];
    #pragma unroll
    for (int nt = 0; nt < 2; ++nt) {
        #pragma unroll
        for (int kt = 0; kt < 8; ++kt) {
            whr[nt][kt] = wsRZ[((w * 4 + 0 + nt) * 8 + kt) * 64 + lane];
            whz[nt][kt] = wsRZ[((w * 4 + 2 + nt) * 8 + kt) * 64 + lane];
            wnn[nt][kt] = wsN[((w * 2 + nt) * 8 + kt) * 64 + lane];
        }
    }
    #pragma unroll
    for (int nt = 0; nt < 2; ++nt) {
        #pragma unroll
        for (int kt = 0; kt < 8; ++kt) {
            asm volatile("" : "+v"(whr[nt][kt]));
            asm volatile("" : "+v"(whz[nt][kt]));
            asm volatile("" : "+v"(wnn[nt][kt]));
        }
    }

    // bhh_n accumulator-init values (C reg j <-> gatech 4*lq+j)
    const float4 bnv0 = *(const float4*)&bhh_f[2 * HDIM + 32 * w + 0  + 4 * lq];
    const float4 bnv1 = *(const float4*)&bhh_f[2 * HDIM + 32 * w + 16 + 4 * lq];

    // constant part of x B-frag: k=8 -> 1.0 (bias multiplier), rest 0
    b8 xc;
    #pragma unroll
    for (int e = 0; e < 8; ++e) xc[e] = (__bf16)0.0f;
    if (lq == 1) xc[0] = (__bf16)1.0f;

    // h master state in registers: (row=l15, ch=32w+16nt+4lq+j)
    f32x4 h0 = zero4, h1 = zero4;

    const int kswz = (8 * lq) ^ ((l15 & 7) << 3);     // B-read swizzle base
    const int wswz = (l15 & 7) << 3;                  // write swizzle
    const b8* wihB = wihL + (w * 6) * 64 + lane;      // this wave's wih in LDS
    const b8* xRow = xB + (blockRow + l15) * WDIM;

    // prefetch x for t=0
    b8 xf = xc;
    if (lane < 16) xf = xRow[0];

    __syncthreads();

    int cur = 0;
    for (int t = 0; t < WDIM; ++t) {
        // prefetch next step's x early (hides L2 latency under MFMA)
        b8 xn = xc;
        if (lane < 16) xn = xRow[(t + 1) & 127];

        // wih frags from LDS (consumed by x-part MFMAs right away)
        b8 wfr0 = wihB[0 * 64], wfr1 = wihB[1 * 64];
        b8 wfz0 = wihB[2 * 64], wfz1 = wihB[3 * 64];
        b8 wfn0 = wihB[4 * 64], wfn1 = wihB[5 * 64];

        // x-part first (includes r,z biases via k=8 slot)
        f32x4 aR0 = MFMA(wfr0, xf, zero4);
        f32x4 aR1 = MFMA(wfr1, xf, zero4);
        f32x4 aZ0 = MFMA(wfz0, xf, zero4);
        f32x4 aZ1 = MFMA(wfz1, xf, zero4);
        f32x4 aNX0 = MFMA(wfn0, xf, zero4);
        f32x4 aNX1 = MFMA(wfn1, xf, zero4);

        f32x4 aNH0, aNH1;
        aNH0[0] = bnv0.x; aNH0[1] = bnv0.y; aNH0[2] = bnv0.z; aNH0[3] = bnv0.w;
        aNH1[0] = bnv1.x; aNH1[1] = bnv1.y; aNH1[2] = bnv1.z; aNH1[3] = bnv1.w;

        const __bf16* hc = hbB + cur * 4096 + l15 * 256;
        #pragma unroll
        for (int kt = 0; kt < 8; ++kt) {
            b8 hfrag = *(const b8*)(hc + ((kt << 5) ^ kswz));
            aR0  = MFMA(whr[0][kt], hfrag, aR0);
            aR1  = MFMA(whr[1][kt], hfrag, aR1);
            aZ0  = MFMA(whz[0][kt], hfrag, aZ0);
            aZ1  = MFMA(whz[1][kt], hfrag, aZ1);
            aNH0 = MFMA(wnn[0][kt], hfrag, aNH0);
            aNH1 = MFMA(wnn[1][kt], hfrag, aNH1);
        }

        // gate fusion (h master in regs)
        __bf16* hn = hbB + (cur ^ 1) * 4096;
        b4 v0, v1;
        #pragma unroll
        for (int j = 0; j < 4; ++j) {
            float r = sig_(aR0[j]);
            float z = sig_(aZ0[j]);
            float n = tanh_(fmaf(r, aNH0[j], aNX0[j]));
            float hv = n + z * (h0[j] - n);
            h0[j] = hv; v0[j] = (__bf16)hv;
            r = sig_(aR1[j]);
            z = sig_(aZ1[j]);
            n = tanh_(fmaf(r, aNH1[j], aNX1[j]));
            hv = n + z * (h1[j] - n);
            h1[j] = hv; v1[j] = (__bf16)hv;
        }
        *(b4*)(hn + l15 * 256 + ((32 * w + 0  + 4 * lq) ^ wswz)) = v0;
        *(b4*)(hn + l15 * 256 + ((32 * w + 16 + 4 * lq) ^ wswz)) = v1;

        xf = xn;
        cur ^= 1;
        __syncthreads();
    }

    // ---- write forward h (f32 regs) into lastb cols [0,256) ----
    {
        b4 v0, v1;
        #pragma unroll
        for (int j = 0; j < 4; ++j) { v0[j] = (__bf16)h0[j]; v1[j] = (__bf16)h1[j]; }
        *(b4*)(&lastb[l15][0] + ((32 * w + 0  + 4 * lq) ^ wswz)) = v0;
        *(b4*)(&lastb[l15][0] + ((32 * w + 16 + 4 * lq) ^ wswz)) = v1;
    }

    // ---- backward cell (h0=0, one step on x[:,127,:]) -> lastb cols [256,512) ----
    {
        const int trow = tid >> 5;           // 0..15
        const int cb = tid & 31;
        const float4* xr = (const float4*)(x + (blockRow + trow) * WDIM * FDIM + 127 * FDIM);
        float4 xv0 = xr[0], xv1 = xr[1];
        const float4* wb = (const float4*)Wih_b;
        #pragma unroll
        for (int jj = 0; jj < 8; ++jj) {
            int ch = cb + 32 * jj;
            float4 a0 = wb[ch * 2],              a1 = wb[ch * 2 + 1];
            float4 b0 = wb[(HDIM + ch) * 2],     b1 = wb[(HDIM + ch) * 2 + 1];
            float4 c0 = wb[(2 * HDIM + ch) * 2], c1 = wb[(2 * HDIM + ch) * 2 + 1];
            float ir = bih_b[ch]
                + xv0.x * a0.x + xv0.y * a0.y + xv0.z * a0.z + xv0.w * a0.w
                + xv1.x * a1.x + xv1.y * a1.y + xv1.z * a1.z + xv1.w * a1.w;
            float iz = bih_b[HDIM + ch]
                + xv0.x * b0.x + xv0.y * b0.y + xv0.z * b0.z + xv0.w * b0.w
                + xv1.x * b1.x + xv1.y * b1.y + xv1.z * b1.z + xv1.w * b1.w;
            float inn = bih_b[2 * HDIM + ch]
                + xv0.x * c0.x + xv0.y * c0.y + xv0.z * c0.z + xv0.w * c0.w
                + xv1.x * c1.x + xv1.y * c1.y + xv1.z * c1.z + xv1.w * c1.w;
            float r = sig_(ir + bhh_b[ch]);
            float z = sig_(iz + bhh_b[HDIM + ch]);
            float n = tanh_(fmaf(r, bhh_b[2 * HDIM + ch], inn));
            float hbw = (1.0f - z) * n;
            int c2 = HDIM + ch;
            lastb[trow][c2 ^ ((trow & 7) << 3)] = (__bf16)hbw;
        }
    }
    __syncthreads();

    // ---- projection: y = gelu(last @ Wp^T + bp); wave w -> cols [32w,32w+32) ----
    {
        f32x4 pacc[2];
        #pragma unroll
        for (int nt = 0; nt < 2; ++nt) {
            int col = 32 * w + nt * 16 + l15;
            float b = bp[col];
            pacc[nt][0] = b; pacc[nt][1] = b; pacc[nt][2] = b; pacc[nt][3] = b;
        }
        #pragma unroll
        for (int kt = 0; kt < 16; ++kt) {
            int c = (kt * 32 + lq * 8) ^ ((l15 & 7) << 3);
            b8 a = *(const b8*)&lastb[l15][c];
            #pragma unroll
            for (int nt = 0; nt < 2; ++nt)
                pacc[nt] = MFMA(a, wsWP[((2 * w + nt) * 16 + kt) * 64 + lane], pacc[nt]);
        }
        #pragma unroll
        for (int nt = 0; nt < 2; ++nt) {
            int col = 32 * w + nt * 16 + l15;
            #pragma unroll
            for (int j = 0; j < 4; ++j) {
                int row = lq * 4 + j;
                float v = pacc[nt][j];
                ybuf[row][col] = 0.5f * v * (1.0f + erff(v * 0.70710678118f));
            }
        }
    }
    __syncthreads();

    // ---- LayerNorm: one wave per 2 rows ----
    #pragma unroll
    for (int rr = 0; rr < 2; ++rr) {
        int row = 2 * w + rr;
        float v[4];
        float s = 0.0f, sq = 0.0f;
        #pragma unroll
        for (int m = 0; m < 4; ++m) {
            v[m] = ybuf[row][lane + 64 * m];
            s += v[m];
            sq += v[m] * v[m];
        }
        #pragma unroll
        for (int off = 32; off >= 1; off >>= 1) {
            s  += __shfl_xor(s, off, 64);
            sq += __shfl_xor(sq, off, 64);
        }
        float mu = s * (1.0f / 256.0f);
        float var = sq * (1.0f / 256.0f) - mu * mu;
        float rs = rsqrtf(var + 1e-5f);
        float* orow = out + (blockRow + row) * HDIM;
        #pragma unroll
        for (int m = 0; m < 4; ++m) {
            int cc = lane + 64 * m;
            orow[cc] = (v[m] - mu) * rs * gamma[cc] + beta[cc];
        }
    }
}

extern "C" void kernel_launch(void* const* d_in, const int* in_sizes, int n_in,
                              void* d_out, int out_size, void* d_ws, size_t ws_size,
                              hipStream_t stream)
{
    const float* x     = (const float*)d_in[0];
    const float* Wih_f = (const float*)d_in[1];
    const float* Whh_f = (const float*)d_in[2];
    const float* bih_f = (const float*)d_in[3];
    const float* bhh_f = (const float*)d_in[4];
    const float* Wih_b = (const float*)d_in[5];
    // d_in[6] = Whh_b unused: h0=0 so gh_b = bhh_b exactly
    const float* bih_b = (const float*)d_in[7];
    const float* bhh_b = (const float*)d_in[8];
    const float* Wp    = (const float*)d_in[9];
    const float* bp    = (const float*)d_in[10];
    const float* gamma = (const float*)d_in[11];
    const float* beta  = (const float*)d_in[12];
    float* out = (float*)d_out;
    unsigned char* ws = (unsigned char*)d_ws;

    // allow 64KB dynamic LDS (host-side attribute, graph-capture safe)
    hipFuncSetAttribute((const void*)gru_main_kernel,
                        hipFuncAttributeMaxDynamicSharedMemorySize, SMEM_BYTES);

    const int packItems = 16384 + 8192 + 3072 + 16384 + 262144;   // 306176
    hipLaunchKernelGGL(pack_kernel, dim3((packItems + 255) / 256), dim3(256), 0, stream,
                       x, Wih_f, Whh_f, bih_f, bhh_f, Wp, ws);
    hipLaunchKernelGGL(gru_main_kernel, dim3(BDIM / 16), dim3(512), SMEM_BYTES, stream,
                       x, bhh_f, Wih_b, bih_b, bhh_b, bp, gamma, beta, ws, out);
}

// Round 6
// 261.790 us; speedup vs baseline: 1.1810x; 1.1810x over previous
//
#include <hip/hip_runtime.h>
#include <hip/hip_bf16.h>

#define BDIM 2048
#define WDIM 128
#define FDIM 8
#define HDIM 256

typedef __bf16 b8 __attribute__((ext_vector_type(8)));
typedef __bf16 b4 __attribute__((ext_vector_type(4)));
typedef float f32x4 __attribute__((ext_vector_type(4)));

// workspace layout (bytes), all 16B aligned
#define OFF_RZ  0                 // 256 frags * 1KB (r,z Whh A-frags)
#define OFF_N   262144            // 128 frags * 1KB (n Whh A-frags -> LDS)
#define OFF_WIH 393216            // 48 frags * 1KB  (Wih A-frags + bias in k=8, L2-streamed)
#define OFF_WP  442368            // 256 frags * 1KB (Wp B-frags)
#define OFF_XB  704512            // 2048*128*8 bf16 = 4194304
// total 4,898,816 B

// dynamic LDS: [0,8K) h dbuf (2x4KB) ; [8K,136K) n-gate frags (16 waves x 8 x 1KB)
// tail overlay: [0,8K) lastb[8][512] bf16 ; [8K,16K) ybuf[8][256] f32
#define SMEM_BYTES 139264

#define MFMA(a,b,c) __builtin_amdgcn_mfma_f32_16x16x32_bf16((a),(b),(c),0,0,0)

static __device__ __forceinline__ float sig_(float v) {
    return __builtin_amdgcn_rcpf(1.0f + __expf(-v));
}
static __device__ __forceinline__ float tanh_(float v) {
    // tanh(v) = 1 - 2/(exp(2v)+1); saturates correctly at +-inf
    return fmaf(-2.0f, __builtin_amdgcn_rcpf(1.0f + __expf(2.0f * v)), 1.0f);
}

// ---------------- pack: weights/x -> bf16 MFMA fragments (unchanged layouts) ----------------
// A-frag (16x16x32): lane l holds A[i = l&15][k = kt*32 + (l>>4)*8 + e]
// B-frag:            lane l holds B[k = kt*32 + (l>>4)*8 + e][j = l&15]
__global__ void pack_kernel(const float* __restrict__ x,
                            const float* __restrict__ Wih_f,
                            const float* __restrict__ Whh_f,
                            const float* __restrict__ bih_f,
                            const float* __restrict__ bhh_f,
                            const float* __restrict__ Wp,
                            unsigned char* __restrict__ ws)
{
    int idx = blockIdx.x * 256 + threadIdx.x;
    if (idx < 16384) {                       // r,z Whh A-frags: f = (p*4+2g+nt)*8+kt, p=mtile>>1
        int l = idx & 63, f = idx >> 6;
        int kt = f & 7, nt = (f >> 3) & 1, g = (f >> 4) & 1, p = f >> 5;
        int gch = g * HDIM + 32 * p + 16 * nt + (l & 15);
        int kb = kt * 32 + (l >> 4) * 8;
        b8 v;
        #pragma unroll
        for (int e = 0; e < 8; ++e) v[e] = (__bf16)Whh_f[gch * HDIM + kb + e];
        ((b8*)(ws + OFF_RZ))[idx] = v;
    } else if (idx < 24576) {                // n Whh A-frags: f = mtile*8+kt
        int j = idx - 16384;
        int l = j & 63, f = j >> 6;
        int kt = f & 7, m = f >> 3;
        int gch = 2 * HDIM + 16 * m + (l & 15);
        int kb = kt * 32 + (l >> 4) * 8;
        b8 v;
        #pragma unroll
        for (int e = 0; e < 8; ++e) v[e] = (__bf16)Whh_f[gch * HDIM + kb + e];
        ((b8*)(ws + OFF_N))[j] = v;
    } else if (idx < 27648) {                // Wih A-frags: f = (p*3+g)*2+nt (K=8 real, bias k=8)
        int j = idx - 24576;
        int l = j & 63, f = j >> 6;
        int nt = f & 1, q = f >> 1, g = q % 3, p = q / 3;
        int gch = g * HDIM + 32 * p + 16 * nt + (l & 15);
        int lq = l >> 4;
        b8 v;
        #pragma unroll
        for (int e = 0; e < 8; ++e) v[e] = (__bf16)0.0f;
        if (lq == 0) {
            #pragma unroll
            for (int e = 0; e < 8; ++e) v[e] = (__bf16)Wih_f[gch * FDIM + e];
        } else if (lq == 1) {
            float b = (g == 2) ? bih_f[gch] : (bih_f[gch] + bhh_f[gch]);
            v[0] = (__bf16)b;                // pairs with 1.0 in x B-frag k=8
        }
        ((b8*)(ws + OFF_WIH))[j] = v;
    } else if (idx < 44032) {                // Wp B-frags
        int j = idx - 27648;
        int l = j & 63, nk = j >> 6;
        int NT = nk >> 4, kt = nk & 15;
        int col = NT * 16 + (l & 15);
        int kb = kt * 32 + (l >> 4) * 8;
        b8 v;
        #pragma unroll
        for (int e = 0; e < 8; ++e) v[e] = (__bf16)Wp[col * (2 * HDIM) + kb + e];
        ((b8*)(ws + OFF_WP))[j] = v;
    } else if (idx < 44032 + 262144) {       // x -> bf16 rows [row][t][8]
        int j = idx - 44032;
        const float* src = x + j * 8;
        b8 v;
        #pragma unroll
        for (int e = 0; e < 8; ++e) v[e] = (__bf16)src[e];
        ((b8*)(ws + OFF_XB))[j] = v;
    }
}

// ---------------- fused GRU: 256 blocks x 1024 threads (16 waves), 8 rows/block ----------------
// Wave w (0..15) owns gate channels [16w, 16w+16) of r, z, n.
// r,z Whh pinned in regs (16 frags); n Whh in LDS; Wih streamed from L2.
// 4 waves/SIMD (128-reg budget). Lanes l15>=8 duplicate rows 0-7 (broadcast reads, no writes).
// D[i=gatech][j=batchrow]: lane holds batchrow = l&15, gatech = 16w + 4*(l>>4)+j.
__global__ __launch_bounds__(1024, 4)
void gru_main_kernel(const float* __restrict__ x,
                     const float* __restrict__ bhh_f,
                     const float* __restrict__ Wih_b, const float* __restrict__ bih_b,
                     const float* __restrict__ bhh_b,
                     const float* __restrict__ bp,
                     const float* __restrict__ gamma, const float* __restrict__ beta,
                     const unsigned char* __restrict__ ws,
                     float* __restrict__ out)
{
    extern __shared__ __align__(16) unsigned char smem[];
    __bf16* hbB = (__bf16*)smem;                            // [0,8K) h dbuf 2x4KB
    b8* nlds = (b8*)(smem + 8192);                          // [8K,136K) n frags
    __bf16 (*lastb)[2 * HDIM] = (__bf16(*)[2 * HDIM])smem;  // tail overlay [0,8K)
    float  (*ybuf)[HDIM]      = (float(*)[HDIM])(smem + 8192); // [8K,16K)

    const int tid = threadIdx.x, lane = tid & 63, w = tid >> 6;   // w 0..15
    const int l15 = lane & 15, lq = lane >> 4, r8 = l15 & 7;
    const int blockRow = blockIdx.x * 8;

    const b8* wsRZ = (const b8*)(ws + OFF_RZ);
    const b8* wsN  = (const b8*)(ws + OFF_N);
    const b8* wsWI = (const b8*)(ws + OFF_WIH);
    const b8* wsWP = (const b8*)(ws + OFF_WP);
    const b8* xB   = (const b8*)(ws + OFF_XB);

    const f32x4 zero4 = {0.f, 0.f, 0.f, 0.f};

    // zero h dbuf (8KB)
    if (tid < 512) *(f32x4*)(smem + tid * 16) = zero4;

    // stage this wave's 8 n-gate frags into LDS (one-time)
    {
        const b8* src = wsN + (w * 8) * 64 + lane;
        b8* dst = nlds + (w * 8) * 64 + lane;
        #pragma unroll
        for (int i = 0; i < 8; ++i) dst[i * 64] = src[i * 64];
    }

    // register-resident A-frags: r,z Whh for this wave's 16 channels (16 frags), PINNED
    b8 whr[8], whz[8];
    {
        const int p = w >> 1, nt = w & 1;
        #pragma unroll
        for (int kt = 0; kt < 8; ++kt) {
            whr[kt] = wsRZ[((p * 4 + 0 + nt) * 8 + kt) * 64 + lane];
            whz[kt] = wsRZ[((p * 4 + 2 + nt) * 8 + kt) * 64 + lane];
        }
    }
    #pragma unroll
    for (int kt = 0; kt < 8; ++kt) {
        asm volatile("" : "+v"(whr[kt]));
        asm volatile("" : "+v"(whz[kt]));
    }

    // Wih frag pointers (loop-invariant, L2-resident)
    const int pw = (w >> 1) * 3, ntw = w & 1;
    const b8* wi0 = wsWI + ((pw + 0) * 2 + ntw) * 64 + lane;
    const b8* wi1 = wsWI + ((pw + 1) * 2 + ntw) * 64 + lane;
    const b8* wi2 = wsWI + ((pw + 2) * 2 + ntw) * 64 + lane;

    // bhh_n accumulator-init (C reg j <-> gatech 16w + 4lq + j)
    const float4 bnv = *(const float4*)&bhh_f[2 * HDIM + 16 * w + 4 * lq];

    // constant part of x B-frag: k=8 -> 1.0 (bias multiplier)
    b8 xc;
    #pragma unroll
    for (int e = 0; e < 8; ++e) xc[e] = (__bf16)0.0f;
    if (lq == 1) xc[0] = (__bf16)1.0f;

    // h master state in regs: (row=l15 [dup for >=8], ch=16w+4lq+j)
    f32x4 h0 = zero4;

    const int kswz = (8 * lq) ^ (r8 << 3);            // B-read swizzle base
    const int c0 = 16 * w + 4 * lq;                   // this lane's channel base
    const b8* nW = nlds + (w * 8) * 64 + lane;
    const b8* xRow = xB + (blockRow + r8) * WDIM;

    __syncthreads();

    int cur = 0;
    for (int t = 0; t < WDIM; ++t) {
        // issue x + wih loads early; kt loop covers the latency
        b8 xf = xc;
        if (lane < 16) xf = xRow[t];
        b8 wfr = *wi0, wfz = *wi1, wfn = *wi2;

        f32x4 aR = zero4, aZ = zero4;
        f32x4 aNH;
        aNH[0] = bnv.x; aNH[1] = bnv.y; aNH[2] = bnv.z; aNH[3] = bnv.w;

        const __bf16* hc = hbB + cur * 2048 + r8 * 256;
        #pragma unroll
        for (int kt = 0; kt < 8; ++kt) {
            b8 hfrag = *(const b8*)(hc + ((kt << 5) ^ kswz));
            b8 nf = nW[kt * 64];
            aR  = MFMA(whr[kt], hfrag, aR);
            aZ  = MFMA(whz[kt], hfrag, aZ);
            aNH = MFMA(nf, hfrag, aNH);
        }
        // x-part (+ r,z biases via k=8 slot)
        aR = MFMA(wfr, xf, aR);
        aZ = MFMA(wfz, xf, aZ);
        f32x4 aNX = MFMA(wfn, xf, zero4);

        // gate fusion (h master in regs)
        __bf16* hn = hbB + (cur ^ 1) * 2048;
        b4 v0;
        #pragma unroll
        for (int j = 0; j < 4; ++j) {
            float r = sig_(aR[j]);
            float z = sig_(aZ[j]);
            float n = tanh_(fmaf(r, aNH[j], aNX[j]));
            float hv = n + z * (h0[j] - n);
            h0[j] = hv; v0[j] = (__bf16)hv;
        }
        if (l15 < 8)
            *(b4*)(hn + l15 * 256 + (c0 ^ (l15 << 3))) = v0;

        cur ^= 1;
        __syncthreads();
    }

    // ---- write forward h into lastb cols [0,256) ----
    {
        b4 v0;
        #pragma unroll
        for (int j = 0; j < 4; ++j) v0[j] = (__bf16)h0[j];
        if (l15 < 8)
            *(b4*)(&lastb[l15][0] + (c0 ^ (l15 << 3))) = v0;
    }

    // ---- backward cell (h0=0, one step on x[:,127,:]) -> lastb cols [256,512) ----
    {
        const int trow = tid >> 7;           // 0..7
        const int cb = tid & 127;
        const float4* xr = (const float4*)(x + (blockRow + trow) * WDIM * FDIM + 127 * FDIM);
        float4 xv0 = xr[0], xv1 = xr[1];
        const float4* wb = (const float4*)Wih_b;
        #pragma unroll
        for (int jj = 0; jj < 2; ++jj) {
            int ch = cb + 128 * jj;
            float4 a0 = wb[ch * 2],              a1 = wb[ch * 2 + 1];
            float4 b0 = wb[(HDIM + ch) * 2],     b1 = wb[(HDIM + ch) * 2 + 1];
            float4 c0v = wb[(2 * HDIM + ch) * 2], c1 = wb[(2 * HDIM + ch) * 2 + 1];
            float ir = bih_b[ch]
                + xv0.x * a0.x + xv0.y * a0.y + xv0.z * a0.z + xv0.w * a0.w
                + xv1.x * a1.x + xv1.y * a1.y + xv1.z * a1.z + xv1.w * a1.w;
            float iz = bih_b[HDIM + ch]
                + xv0.x * b0.x + xv0.y * b0.y + xv0.z * b0.z + xv0.w * b0.w
                + xv1.x * b1.x + xv1.y * b1.y + xv1.z * b1.z + xv1.w * b1.w;
            float inn = bih_b[2 * HDIM + ch]
                + xv0.x * c0v.x + xv0.y * c0v.y + xv0.z * c0v.z + xv0.w * c0v.w
                + xv1.x * c1.x + xv1.y * c1.y + xv1.z * c1.z + xv1.w * c1.w;
            float r = sig_(ir + bhh_b[ch]);
            float z = sig_(iz + bhh_b[HDIM + ch]);
            float n = tanh_(fmaf(r, bhh_b[2 * HDIM + ch], inn));
            float hbw = (1.0f - z) * n;
            int c2 = HDIM + ch;
            lastb[trow][c2 ^ (trow << 3)] = (__bf16)hbw;
        }
    }
    __syncthreads();

    // ---- projection: y = gelu(last @ Wp^T + bp); wave w -> cols [16w,16w+16) ----
    {
        int col = 16 * w + l15;
        float b = bp[col];
        f32x4 pacc;
        pacc[0] = b; pacc[1] = b; pacc[2] = b; pacc[3] = b;
        #pragma unroll
        for (int kt = 0; kt < 16; ++kt) {
            int c = (kt * 32 + lq * 8) ^ (r8 << 3);
            b8 a = *(const b8*)&lastb[r8][c];
            pacc = MFMA(a, wsWP[(w * 16 + kt) * 64 + lane], pacc);
        }
        if (lq < 2) {
            #pragma unroll
            for (int j = 0; j < 4; ++j) {
                int row = lq * 4 + j;
                float v = pacc[j];
                ybuf[row][col] = 0.5f * v * (1.0f + erff(v * 0.70710678118f));
            }
        }
    }
    __syncthreads();

    // ---- LayerNorm: waves 0..7, one row each ----
    if (w < 8) {
        int row = w;
        float v[4];
        float s = 0.0f, sq = 0.0f;
        #pragma unroll
        for (int m = 0; m < 4; ++m) {
            v[m] = ybuf[row][lane + 64 * m];
            s += v[m];
            sq += v[m] * v[m];
        }
        #pragma unroll
        for (int off = 32; off >= 1; off >>= 1) {
            s  += __shfl_xor(s, off, 64);
            sq += __shfl_xor(sq, off, 64);
        }
        float mu = s * (1.0f / 256.0f);
        float var = sq * (1.0f / 256.0f) - mu * mu;
        float rs = rsqrtf(var + 1e-5f);
        float* orow = out + (blockRow + row) * HDIM;
        #pragma unroll
        for (int m = 0; m < 4; ++m) {
            int cc = lane + 64 * m;
            orow[cc] = (v[m] - mu) * rs * gamma[cc] + beta[cc];
        }
    }
}

extern "C" void kernel_launch(void* const* d_in, const int* in_sizes, int n_in,
                              void* d_out, int out_size, void* d_ws, size_t ws_size,
                              hipStream_t stream)
{
    const float* x     = (const float*)d_in[0];
    const float* Wih_f = (const float*)d_in[1];
    const float* Whh_f = (const float*)d_in[2];
    const float* bih_f = (const float*)d_in[3];
    const float* bhh_f = (const float*)d_in[4];
    const float* Wih_b = (const float*)d_in[5];
    // d_in[6] = Whh_b unused: h0=0 so gh_b = bhh_b exactly
    const float* bih_b = (const float*)d_in[7];
    const float* bhh_b = (const float*)d_in[8];
    const float* Wp    = (const float*)d_in[9];
    const float* bp    = (const float*)d_in[10];
    const float* gamma = (const float*)d_in[11];
    const float* beta  = (const float*)d_in[12];
    float* out = (float*)d_out;
    unsigned char* ws = (unsigned char*)d_ws;

    // allow 136KB dynamic LDS (host-side attribute, graph-capture safe)
    hipFuncSetAttribute((const void*)gru_main_kernel,
                        hipFuncAttributeMaxDynamicSharedMemorySize, SMEM_BYTES);

    const int packItems = 16384 + 8192 + 3072 + 16384 + 262144;   // 306176
    hipLaunchKernelGGL(pack_kernel, dim3((packItems + 255) / 256), dim3(256), 0, stream,
                       x, Wih_f, Whh_f, bih_f, bhh_f, Wp, ws);
    hipLaunchKernelGGL(gru_main_kernel, dim3(BDIM / 8), dim3(1024), SMEM_BYTES, stream,
                       x, bhh_f, Wih_b, bih_b, bhh_b, bp, gamma, beta, ws, out);
}